// Round 11
// baseline (154.634 us; speedup 1.0000x reference)
//
#include <hip/hip_runtime.h>
#include <math.h>

#define NQ 9
#define KK 3
#define S 16
#define H 128
#define BB 16
#define D 512
#define DD (D*D)

typedef float vfloat4 __attribute__((ext_vector_type(4)));  // native vec for nontemporal

__device__ __forceinline__ float sigf(float x){ return 1.f/(1.f + __expf(-x)); }
// fast tanh: 1 - 2/(e^{2x}+1); exact at +-inf saturation, ~1ulp interior
__device__ __forceinline__ float tanhfast(float x){
  float e = __expf(2.f*x);
  return 1.f - 2.f/(e + 1.f);
}
#define RCP(x)  __builtin_amdgcn_rcpf(x)
#define RSQ(x)  __builtin_amdgcn_rsqf(x)

// DPP-based wave(64) sum reduction (AMD cross-lane sequence): row_shr:1/2/4/8
// inclusive scan, row_bcast:15 (rows 1,3), row_bcast:31 (rows 2,3), total in
// lane 63.
#define DPP_ADD(x, ctrl, rmask) \
  x += __int_as_float(__builtin_amdgcn_update_dpp(0, __float_as_int(x), ctrl, rmask, 0xf, false))

__device__ __forceinline__ float wave_red_sum(float x) {
  DPP_ADD(x, 0x111, 0xf);   // row_shr:1
  DPP_ADD(x, 0x112, 0xf);   // row_shr:2
  DPP_ADD(x, 0x114, 0xf);   // row_shr:4
  DPP_ADD(x, 0x118, 0xf);   // row_shr:8
  DPP_ADD(x, 0x142, 0xa);   // row_bcast:15 -> rows 1,3
  DPP_ADD(x, 0x143, 0xc);   // row_bcast:31 -> rows 2,3
  return __int_as_float(__builtin_amdgcn_readlane(__float_as_int(x), 63));
}
#define RL(v, l) __int_as_float(__builtin_amdgcn_readlane(__float_as_int(v), (l)))
// row_ror:N: source lane = (i - N) mod 16. To read lane (i + half) use 16-half.
#define DPP_ROR(x, n) \
  __int_as_float(__builtin_amdgcn_update_dpp(0, __float_as_int(x), 0x120 + (n), 0xf, 0xf, false))

// W_hh row dot h via readlane broadcast (h register-resident on every wave:
// lane l holds h[2l], h[2l+1]).  4 independent accumulator chains.  SINGLE
// ghh form in the whole kernel (r2/r5/r7/r8 evidence: kernels containing
// both an RL-ghh and an LDS-ghh path spill; uniform path does not).
__device__ __forceinline__ float ghh_rl4(const float4 (&whh)[32],
                                         float h0v, float h1v, float bias) {
  float g0 = bias, g1 = 0.f, g2 = 0.f, g3 = 0.f;
  #pragma unroll
  for (int j = 0; j < 32; ++j) {
    float4 wv = whh[j];
    g0 += wv.x*RL(h0v, 2*j);
    g1 += wv.y*RL(h1v, 2*j);
    g2 += wv.z*RL(h0v, 2*j + 1);
    g3 += wv.w*RL(h1v, 2*j + 1);
  }
  return (g0 + g1) + (g2 + g3);
}

// Owner-wave work for one qubit q: 3 logits (Wp from LDS, per-lane float2,
// 2-way bank alias = free), softmax -> amps, projector coefficients; lane 0
// publishes [K0,K1r,K1i,a1,a2,a3] to kbf[6q..6q+5] and amps to xh.  Runs on
// waves 1-7 in window 1, hidden under wave-0's ghh.  Transient regs only.
__device__ __forceinline__ void qubit_owner(int q, int lane,
                                            float h0v, float h1v,
                                            const float* wp_lds,
                                            const float* bp_lds,
                                            float* kbf, float* xh) {
  float l0, l1, l2;
  {
    const float2 w0 = *(const float2*)&wp_lds[(3*q    )*H + 2*lane];
    const float2 w1 = *(const float2*)&wp_lds[(3*q + 1)*H + 2*lane];
    const float2 w2 = *(const float2*)&wp_lds[(3*q + 2)*H + 2*lane];
    l0 = wave_red_sum(w0.x*h0v + w0.y*h1v) + bp_lds[3*q];
    l1 = wave_red_sum(w1.x*h0v + w1.y*h1v) + bp_lds[3*q + 1];
    l2 = wave_red_sum(w2.x*h0v + w2.y*h1v) + bp_lds[3*q + 2];
  }
  float mx = fmaxf(l0, fmaxf(l1, l2));
  float e0 = __expf(l0 - mx), e1 = __expf(l1 - mx), e2 = __expf(l2 - mx);
  float inv = RCP(e0 + e1 + e2);
  float a1 = sqrtf(e0*inv), a2 = sqrtf(e1*inv), a3 = sqrtf(e2*inv);
  float an = sqrtf(a1*a1 + a2*a2 + a3*a3);
  float t3 = a3 + an;
  float n1 = RSQ(2.f*an*t3);
  if (lane == 0) {
    kbf[6*q + 0] = n1*t3; kbf[6*q + 1] = n1*a1; kbf[6*q + 2] = -n1*a2;
    kbf[6*q + 3] = a1;    kbf[6*q + 4] = a2;    kbf[6*q + 5] = a3;
    xh[9 + 3*q]     = a1;
    xh[9 + 3*q + 1] = a2;
    xh[9 + 3*q + 2] = a3;
  }
}

// ---------------------------------------------------------------------------
// Kernel 1: sequential LSTM + snapshot recurrence, fp32, one block/batch
// (512 thr = 8 waves).  Structure = r10 (owner-softmax) + K-delivery fix:
//  - r10's regression vs r7 (56.0 vs 54.0us) was 27 scattered ds_read_b32 of
//    kb[q][j] threaded through wave-0's collapse chain (LDS latency replaced
//    r7's 1-cyc readlanes).  Fix: wave 0 loads the whole coefficient block
//    with ONE ds_read (kbv = kbf[lane], lanes 0-53) and extracts per-stage
//    K's with inline RL(kbv, 6q+j) -- compile-time lane indices, r7's exact
//    readlane pattern, +1 register, no hoisted array (r4 spill lesson).
//  - owner waves (w-1, and w+6 for w<=2) compute logits+softmax+K in window
//    1, hidden under wave-0's ghh; wave-0's window 2 is pure collapse.
//  - single RL-ghh path everywhere (dual-form kernels spill: r5/r8).
// REGISTER DISCIPLINE: net delta ~+1 reg vs r7; no asm touching whh;
// launch_bounds(512,2).  Spill canary = WRITE_SIZE (must stay ~38 KB).
// Schedule per step (3 barriers, all unconditional):
//   X -> B1 -> cell -> {w1-7: logits+softmax+K publish | w0: own ghh} -> B2
//   -> {w0: kbv load + collapse + emit | w1-7: own ghh} -> B3
// Collapse: deferred-norm halving contraction; qubits 0-2 in register bits,
// q3/q4 via bpermute, q5-q8 via DPP row_ror(16-half);
// s_0 = 2L_0 - |psi0|^2 ; s_q = 2 L_q/L_{q-1} - 1 (projector completeness).
// Reference semantics: every timestep's collapse starts from pristine psi0.
// ---------------------------------------------------------------------------
__global__ __launch_bounds__(512, 2)
void seq_kernel(const float* __restrict__ snapshot,
                const float* __restrict__ bcv,
                const float* __restrict__ rho,
                const float* __restrict__ h0,
                const float* __restrict__ c0,
                const float* __restrict__ W_ih,
                const float* __restrict__ W_hh,
                const float* __restrict__ b_ih,
                const float* __restrict__ b_hh,
                const float* __restrict__ Wp,
                const float* __restrict__ bp,
                float4* __restrict__ mats,      // [BB][S][NQ]
                float* __restrict__ last_bv)
{
  const int b    = blockIdx.x;
  const int tid  = threadIdx.x;
  const int lane = tid & 63;
  const int w    = tid >> 6;

  __shared__ __align__(16) float xh[36];      // x only: snap(9) + amps(27)
  __shared__ float gbuf[512];
  __shared__ __align__(16) float wp_lds[27*H];  // Wp staged (13.5 KB)
  __shared__ float bp_lds[27];
  __shared__ float kbf[54];                   // flat [q][K0,K1r,K1i,a1,a2,a3]

  // ---- weights into registers (reused all 15 steps)
  float4 wih[9], whh[32];
  {
    const float4* wi = (const float4*)(W_ih + tid*36);
    #pragma unroll
    for (int k = 0; k < 9; ++k) wih[k] = wi[k];
    const float4* wh = (const float4*)(W_hh + tid*H);
    #pragma unroll
    for (int k = 0; k < 32; ++k) whh[k] = wh[k];
  }
  const float bias = b_ih[tid] + b_hh[tid];

  // ---- stage Wp and bp into LDS (one-time; frees wpv/bpv registers)
  for (int idx = tid; idx < 27*H; idx += 512) wp_lds[idx] = Wp[idx];
  if (tid < 27) bp_lds[tid] = bp[tid];

  // ---- c and h register-resident on EVERY wave (redundant copies, 2/lane)
  float cc0 = c0[b*H + 2*lane], cc1 = c0[b*H + 2*lane + 1];
  float h0v = h0[b*H + 2*lane], h1v = h0[b*H + 2*lane + 1];

  // ---- pristine psi0 in wave-0 registers: flat = j*64 + lane
  float pr0[8], pi0[8], norm0 = 0.f;
  if (w == 0) {
    #pragma unroll
    for (int j = 0; j < 8; ++j) {
      pr0[j] = rho[b*1024 + j*64 + lane];
      pi0[j] = rho[b*1024 + 512 + j*64 + lane];
    }
    float ls = 0.f;
    #pragma unroll
    for (int j = 0; j < 8; ++j) ls += pr0[j]*pr0[j] + pi0[j]*pi0[j];
    norm0 = wave_red_sum(ls);
  }

  // ---- init x in LDS; t=0 mats straight from global inputs
  if (tid < NQ)  xh[tid]      = snapshot[b*NQ + tid];
  if (tid < 27)  xh[NQ + tid] = bcv[b*27 + tid];
  if (tid < NQ) {
    float s  = snapshot[b*NQ + tid];
    float v0 = bcv[b*27 + tid*3];
    float v1 = bcv[b*27 + tid*3 + 1];
    float v2 = bcv[b*27 + tid*3 + 2];
    mats[(b*S + 0)*NQ + tid] = make_float4(
        0.5f*(1.f + 3.f*s*v2), 1.5f*s*v0, -1.5f*s*v1, 0.5f*(1.f - 3.f*s*v2));
  }
  __syncthreads();                                        // B0: LDS staged

  // ---- pre-loop ghh from h0 registers (readlane broadcast, all waves)
  float ghh = ghh_rl4(whh, h0v, h1v, bias);

  for (int t = 1; t < S; ++t) {
    // ---- X: finish gates = ghh + W_ih * x   (9 LDS b128 reads)
    {
      const float4* x4 = (const float4*)xh;
      float g0 = ghh, g1 = 0.f, g2 = 0.f, g3 = 0.f;
      #pragma unroll
      for (int k = 0; k < 9; ++k) {
        float4 wv = wih[k], xv = x4[k];
        g0 += wv.x*xv.x; g1 += wv.y*xv.y; g2 += wv.z*xv.z; g3 += wv.w*xv.w;
      }
      gbuf[tid] = (g0 + g1) + (g2 + g3);
    }
    __syncthreads();                                      // B1: gbuf ready

    // ---- C: cell update, every wave redundantly (h in registers)
    {
      float2 gI = *(const float2*)(gbuf + 2*lane);
      float2 gF = *(const float2*)(gbuf + 128 + 2*lane);
      float2 gG = *(const float2*)(gbuf + 256 + 2*lane);
      float2 gO = *(const float2*)(gbuf + 384 + 2*lane);
      cc0 = sigf(gF.x)*cc0 + sigf(gI.x)*tanhfast(gG.x);
      cc1 = sigf(gF.y)*cc1 + sigf(gI.y)*tanhfast(gG.y);
      h0v = sigf(gO.x)*tanhfast(cc0);
      h1v = sigf(gO.y)*tanhfast(cc1);
    }
    // ---- window 1: waves 1-7 do their owned qubits' logits+softmax+K
    //      publish; wave 0 computes its own next-step ghh (hidden under it)
    if (w > 0) {
      qubit_owner(w - 1, lane, h0v, h1v, wp_lds, bp_lds, kbf, xh);
      if (w <= 2) qubit_owner(w + 6, lane, h0v, h1v, wp_lds, bp_lds, kbf, xh);
    } else if (t < S - 1) {
      ghh = ghh_rl4(whh, h0v, h1v, bias);
    }
    __syncthreads();                                      // B2: kbf, amps ready

    // ---- wave 0: ONE vector load of the coefficient block, then pure
    //      collapse with inline-RL coefficient extraction (r7 pattern).
    //      (waves 1-7 skip straight to their ghh below -> overlap)
    if (w == 0) {
      float kbv = (lane < 54) ? kbf[lane] : 0.f;   // single ds_read_b32
      float part[9];

      // q0: register bit 2 (no cross-lane)
      float r4[4], i4[4];
      {
        const float K0 = RL(kbv,0), K1r = RL(kbv,1), K1i = RL(kbv,2);
        float lp = 0.f;
        #pragma unroll
        for (int j = 0; j < 4; ++j) {
          r4[j] = K0*pr0[j] + K1r*pr0[j+4] - K1i*pi0[j+4];
          i4[j] = K0*pi0[j] + K1r*pi0[j+4] + K1i*pr0[j+4];
          lp += r4[j]*r4[j] + i4[j]*i4[j];
        }
        part[0] = lp;
      }
      // q1: register bit 1
      float r2[2], i2[2];
      {
        const float K0 = RL(kbv,6), K1r = RL(kbv,7), K1i = RL(kbv,8);
        float lp = 0.f;
        #pragma unroll
        for (int j = 0; j < 2; ++j) {
          r2[j] = K0*r4[j] + K1r*r4[j+2] - K1i*i4[j+2];
          i2[j] = K0*i4[j] + K1r*i4[j+2] + K1i*r4[j+2];
          lp += r2[j]*r2[j] + i2[j]*i2[j];
        }
        part[1] = lp;
      }
      // q2: register bit 0
      float wr, wi_;
      {
        const float K0 = RL(kbv,12), K1r = RL(kbv,13), K1i = RL(kbv,14);
        wr  = K0*r2[0] + K1r*r2[1] - K1i*i2[1];
        wi_ = K0*i2[0] + K1r*i2[1] + K1i*r2[1];
        part[2] = wr*wr + wi_*wi_;
      }
      // q3, q4: partner lane+half via bpermute (half = 32, 16)
      #pragma unroll
      for (int q = 3; q < 5; ++q) {
        const int half = 32 >> (q - 3);
        const float K0 = RL(kbv,6*q), K1r = RL(kbv,6*q+1), K1i = RL(kbv,6*q+2);
        float pr = __shfl(wr,  lane + half, 64);
        float pi = __shfl(wi_, lane + half, 64);
        float nr = K0*wr  + K1r*pr - K1i*pi;
        float ni = K0*wi_ + K1r*pi + K1i*pr;
        wr = nr; wi_ = ni;
        part[q] = (lane < half) ? (nr*nr + ni*ni) : 0.f;
      }
      // q5..q8: partner lane+half via row_ror:(16-half)  [source = i+half]
      #pragma unroll
      for (int q = 5; q < NQ; ++q) {
        const int half = 32 >> (q - 3);
        const float K0 = RL(kbv,6*q), K1r = RL(kbv,6*q+1), K1i = RL(kbv,6*q+2);
        float pr, pi;
        if      (q == 5) { pr = DPP_ROR(wr, 8);  pi = DPP_ROR(wi_, 8);  }
        else if (q == 6) { pr = DPP_ROR(wr, 12); pi = DPP_ROR(wi_, 12); }
        else if (q == 7) { pr = DPP_ROR(wr, 14); pi = DPP_ROR(wi_, 14); }
        else             { pr = DPP_ROR(wr, 15); pi = DPP_ROR(wi_, 15); }
        float nr = K0*wr  + K1r*pr - K1i*pi;
        float ni = K0*wi_ + K1r*pi + K1i*pr;
        wr = nr; wi_ = ni;
        part[q] = (lane < half) ? (nr*nr + ni*ni) : 0.f;
      }
      // batched norm reductions (independent DPP chains)
      float L[9];
      #pragma unroll
      for (int q = 0; q < NQ; ++q) L[q] = wave_red_sum(part[q]);
      // s values: independent rcp per qubit (parallel, not a divide chain)
      float sv = 2.f*L[0] - norm0;
      #pragma unroll
      for (int q = 1; q < NQ; ++q) {
        float r = 2.f*L[q]*RCP(L[q-1]) - 1.f;
        sv = (lane == q) ? r : sv;
      }
      // emit: new snap and mats row for this t (amps already published by
      // owners; per-lane kbf reads, off the critical-chain head)
      if (lane < NQ) {
        float A1 = kbf[6*lane + 3], A2 = kbf[6*lane + 4], A3 = kbf[6*lane + 5];
        xh[lane] = sv;
        mats[(b*S + t)*NQ + lane] = make_float4(
            0.5f*(1.f + 3.f*sv*A3), 1.5f*sv*A1,
            -1.5f*sv*A2,            0.5f*(1.f - 3.f*sv*A3));
      }
    } else if (t < S - 1) {
      // ---- waves 1-7: next-step ghh from register h (runs during
      //      wave 0's collapse)
      ghh = ghh_rl4(whh, h0v, h1v, bias);
    }
    __syncthreads();                                      // B3: xh ready
  }

  if (tid < 27) last_bv[b*27 + tid] = xh[9 + tid];
}

// ---------------------------------------------------------------------------
// Kernel 2: out[b] = (1/S) sum_t Top(q0..3,16x16) (x) Bot(q4..8,32x32).
// v5: 2 rT x 4 rB rows per block, grid (64,16) = 1024 blocks.
// Staging writes are ENTRY-STRIDED (thread e writes entries e+512i) so
// consecutive lanes hit consecutive float2 -> 2-way bank aliasing (free).
// b128 bot reads (8 distinct addrs/wave = broadcast), nontemporal stores.
// ---------------------------------------------------------------------------
__device__ __forceinline__ void herm_entry(float4 m, int rb, int cb, float& er, float& ei) {
  if (rb == 0) { if (cb == 0) { er = m.x; ei = 0.f; } else { er = m.y; ei = m.z; } }
  else         { if (cb == 0) { er = m.y; ei = -m.z; } else { er = m.w; ei = 0.f; } }
}

__device__ __forceinline__ void nt_store4(float* p, float x, float y, float z, float w) {
  vfloat4 v; v.x = x; v.y = y; v.z = z; v.w = w;
  __builtin_nontemporal_store(v, (vfloat4*)p);
}

__global__ __launch_bounds__(512, 2)
void kron_kernel(const float4* __restrict__ mats_g, float* __restrict__ out)
{
  const int b   = blockIdx.y;
  const int bm  = blockIdx.x;          // rTp = bm>>3 (rT pair), rg = bm&7 (rB grp)
  const int tid = threadIdx.x;
  const int rTp = bm >> 3;
  const int rg  = bm & 7;

  __shared__ float4 matsh[S*NQ];                  // 2.3 KB
  __shared__ float2 top[S][2][16];                // 4 KB  [t][rTi][cT]
  __shared__ __align__(16) float2 bot[4][S][32];  // 16 KB [r][t][cB]

  if (tid < S*NQ) matsh[tid] = mats_g[b*S*NQ + tid];
  __syncthreads();

  {                                    // top: 512 entries, one per thread
    int t = tid >> 5, rTi = (tid >> 4) & 1, cT = tid & 15;
    int rT = rTp*2 + rTi;
    float re = 1.f, im = 0.f;
    #pragma unroll
    for (int q = 0; q < 4; ++q) {
      int rb = (rT >> (3 - q)) & 1, cb = (cT >> (3 - q)) & 1;
      float er, ei; herm_entry(matsh[t*NQ + q], rb, cb, er, ei);
      float nr = re*er - im*ei; im = re*ei + im*er; re = nr;
    }
    top[t][rTi][cT] = make_float2(re, im);
  }
  // bot: 2048 entries, entry-strided (conflict-free writes)
  #pragma unroll
  for (int i = 0; i < 4; ++i) {
    int n  = tid + 512*i;
    int r_ = n >> 9, t_ = (n >> 5) & 15, cB = n & 31;
    int rB = rg*4 + r_;
    float re = 1.f, im = 0.f;
    #pragma unroll
    for (int q = 0; q < 5; ++q) {
      int rb = (rB >> (4 - q)) & 1, cb = (cB >> (4 - q)) & 1;
      float er, ei; herm_entry(matsh[t_*NQ + 4 + q], rb, cb, er, ei);
      float nr = re*er - im*ei; im = re*ei + im*er; re = nr;
    }
    bot[r_][t_][cB] = make_float2(re, im);
  }
  __syncthreads();

  const int rb = tid >> 7;             // rB index within block (0..3)
  const int c0 = (tid & 127) << 2;     // 4 consecutive cols
  const int cT = c0 >> 5, cB = c0 & 31;
  float4 a0r = make_float4(0,0,0,0), a0i = make_float4(0,0,0,0);
  float4 a1r = make_float4(0,0,0,0), a1i = make_float4(0,0,0,0);
  #pragma unroll
  for (int t = 0; t < S; ++t) {
    float4 b01 = *(const float4*)&bot[rb][t][cB];      // cols cB, cB+1
    float4 b23 = *(const float4*)&bot[rb][t][cB + 2];  // cols cB+2, cB+3
    float2 tA = top[t][0][cT];
    float2 tB = top[t][1][cT];
    a0r.x += tA.x*b01.x - tA.y*b01.y;  a0i.x += tA.x*b01.y + tA.y*b01.x;
    a0r.y += tA.x*b01.z - tA.y*b01.w;  a0i.y += tA.x*b01.w + tA.y*b01.z;
    a0r.z += tA.x*b23.x - tA.y*b23.y;  a0i.z += tA.x*b23.y + tA.y*b23.x;
    a0r.w += tA.x*b23.z - tA.y*b23.w;  a0i.w += tA.x*b23.w + tA.y*b23.z;
    a1r.x += tB.x*b01.x - tB.y*b01.y;  a1i.x += tB.x*b01.y + tB.y*b01.x;
    a1r.y += tB.x*b01.z - tB.y*b01.w;  a1i.y += tB.x*b01.w + tB.y*b01.z;
    a1r.z += tB.x*b23.x - tB.y*b23.y;  a1i.z += tB.x*b23.y + tB.y*b23.x;
    a1r.w += tB.x*b23.z - tB.y*b23.w;  a1i.w += tB.x*b23.w + tB.y*b23.z;
  }
  const float invS = 1.f/16.f;
  const int rowA = (rTp*2)*32 + rg*4 + rb;   // rT = 2*rTp
  const int rowB = rowA + 32;                // rT = 2*rTp + 1
  size_t baseA = ((size_t)b*2)*DD + (size_t)rowA*D + c0;
  size_t baseB = ((size_t)b*2)*DD + (size_t)rowB*D + c0;
  nt_store4(out + baseA,      a0r.x*invS, a0r.y*invS, a0r.z*invS, a0r.w*invS);
  nt_store4(out + baseA + DD, a0i.x*invS, a0i.y*invS, a0i.z*invS, a0i.w*invS);
  nt_store4(out + baseB,      a1r.x*invS, a1r.y*invS, a1r.z*invS, a1r.w*invS);
  nt_store4(out + baseB + DD, a1i.x*invS, a1i.y*invS, a1i.z*invS, a1i.w*invS);
}

extern "C" void kernel_launch(void* const* d_in, const int* in_sizes, int n_in,
                              void* d_out, int out_size, void* d_ws, size_t ws_size,
                              hipStream_t stream) {
  const float* snapshot = (const float*)d_in[0];
  const float* bcv      = (const float*)d_in[1];
  const float* rho      = (const float*)d_in[2];
  const float* h0       = (const float*)d_in[3];
  const float* c0       = (const float*)d_in[4];
  const float* W_ih     = (const float*)d_in[5];
  const float* W_hh     = (const float*)d_in[6];
  const float* b_ih     = (const float*)d_in[7];
  const float* b_hh     = (const float*)d_in[8];
  const float* Wp       = (const float*)d_in[9];
  const float* bp       = (const float*)d_in[10];

  float*  out     = (float*)d_out;
  float4* mats    = (float4*)d_ws;                 // 16*16*9 float4 = 36 KB
  float*  last_bv = out + (size_t)BB*2*DD;         // output chunk 1

  seq_kernel<<<BB, 512, 0, stream>>>(snapshot, bcv, rho, h0, c0,
                                     W_ih, W_hh, b_ih, b_hh, Wp, bp,
                                     mats, last_bv);

  dim3 grid(64, BB);
  kron_kernel<<<grid, 512, 0, stream>>>(mats, out);
}

// Round 12
// 151.710 us; speedup vs baseline: 1.0193x; 1.0193x over previous
//
#include <hip/hip_runtime.h>
#include <math.h>

#define NQ 9
#define KK 3
#define S 16
#define H 128
#define BB 16
#define D 512
#define DD (D*D)

typedef float vfloat4 __attribute__((ext_vector_type(4)));  // native vec for nontemporal

__device__ __forceinline__ float sigf(float x){ return 1.f/(1.f + __expf(-x)); }
// fast tanh: 1 - 2/(e^{2x}+1); exact at +-inf saturation, ~1ulp interior
__device__ __forceinline__ float tanhfast(float x){
  float e = __expf(2.f*x);
  return 1.f - 2.f/(e + 1.f);
}
#define RCP(x)  __builtin_amdgcn_rcpf(x)
#define RSQ(x)  __builtin_amdgcn_rsqf(x)

// DPP-based wave(64) sum reduction (AMD cross-lane sequence): row_shr:1/2/4/8
// inclusive scan, row_bcast:15 (rows 1,3), row_bcast:31 (rows 2,3), total in
// lane 63.
#define DPP_ADD(x, ctrl, rmask) \
  x += __int_as_float(__builtin_amdgcn_update_dpp(0, __float_as_int(x), ctrl, rmask, 0xf, false))

__device__ __forceinline__ float wave_red_sum(float x) {
  DPP_ADD(x, 0x111, 0xf);   // row_shr:1
  DPP_ADD(x, 0x112, 0xf);   // row_shr:2
  DPP_ADD(x, 0x114, 0xf);   // row_shr:4
  DPP_ADD(x, 0x118, 0xf);   // row_shr:8
  DPP_ADD(x, 0x142, 0xa);   // row_bcast:15 -> rows 1,3
  DPP_ADD(x, 0x143, 0xc);   // row_bcast:31 -> rows 2,3
  return __int_as_float(__builtin_amdgcn_readlane(__float_as_int(x), 63));
}
#define RL(v, l) __int_as_float(__builtin_amdgcn_readlane(__float_as_int(v), (l)))
// row_ror:N: source lane = (i - N) mod 16. To read lane (i + half) use 16-half.
#define DPP_ROR(x, n) \
  __int_as_float(__builtin_amdgcn_update_dpp(0, __float_as_int(x), 0x120 + (n), 0xf, 0xf, false))

// W_hh row dot h via readlane broadcast (h register-resident on every wave:
// lane l holds h[2l], h[2l+1]).  4 independent accumulator chains: dep depth
// 32 FMAs instead of 128.  Transient registers only.  SINGLE ghh form in the
// whole kernel (r2/r5/r7/r8 evidence: kernels containing both an RL-ghh and
// an LDS-ghh path spill; uniform path does not).
__device__ __forceinline__ float ghh_rl4(const float4 (&whh)[32],
                                         float h0v, float h1v, float bias) {
  float g0 = bias, g1 = 0.f, g2 = 0.f, g3 = 0.f;
  #pragma unroll
  for (int j = 0; j < 32; ++j) {
    float4 wv = whh[j];
    g0 += wv.x*RL(h0v, 2*j);
    g1 += wv.y*RL(h1v, 2*j);
    g2 += wv.z*RL(h0v, 2*j + 1);
    g3 += wv.w*RL(h1v, 2*j + 1);
  }
  return (g0 + g1) + (g2 + g3);
}

// ---------------------------------------------------------------------------
// Kernel 1: sequential LSTM + snapshot recurrence, fp32, one block/batch
// (512 thr = 8 waves).  SESSION-BEST STRUCTURE (r7, 54.0us seq / 152.4us
// total, no spill).  Two register-neutral changes vs the r0 baseline:
//  (a) prj's 27 units owned by waves 1-7 (u=(w-1)+7i); wave 0 computes its
//      own next-step ghh in that slot (hidden under the helpers' prj), so
//      wave-0's post-collapse tail ghh disappears from its serial chain.
//  (b) ghh accumulator split 4 ways (dep chain 128 -> 32 FMAs).
// Bracketing experiments (all regressed or spilled):
//  r2: LDS-h ghh on wave-0 chain (+4.6us); r3/r6: offload wave-0's gate rows
//  (spill); r4: K-coefficient hoist (spill); r5/r8: dual ghh forms (spill);
//  r10/r11: owner-softmax in window 1 (+2us -- window-1 gate exceeded).
// REGISTER DISCIPLINE: 128-VGPR arch cap at (512,2); r7 sits at 120 with
// whh AGPR-parked.  No new persistent registers, no inline asm touching whh.
// Spill canary = WRITE_SIZE (must stay ~38 KB).
// Schedule per step (3 barriers, all unconditional):
//   X -> B1 -> cell -> {w1-7: prj | w0: own ghh} -> B2 ->
//   {w0: softmax+collapse+emit | w1-7: own ghh} -> B3
// Collapse: deferred-norm halving contraction; qubits 0-2 in register bits,
// q3/q4 via bpermute, q5-q8 via DPP row_ror(16-half);
// s_0 = 2L_0 - |psi0|^2 ; s_q = 2 L_q/L_{q-1} - 1 (projector completeness).
// Reference semantics: every timestep's collapse starts from pristine psi0.
// ---------------------------------------------------------------------------
__global__ __launch_bounds__(512, 2)
void seq_kernel(const float* __restrict__ snapshot,
                const float* __restrict__ bcv,
                const float* __restrict__ rho,
                const float* __restrict__ h0,
                const float* __restrict__ c0,
                const float* __restrict__ W_ih,
                const float* __restrict__ W_hh,
                const float* __restrict__ b_ih,
                const float* __restrict__ b_hh,
                const float* __restrict__ Wp,
                const float* __restrict__ bp,
                float4* __restrict__ mats,      // [BB][S][NQ]
                float* __restrict__ last_bv)
{
  const int b    = blockIdx.x;
  const int tid  = threadIdx.x;
  const int lane = tid & 63;
  const int w    = tid >> 6;

  __shared__ __align__(16) float xh[36];      // x only: snap(9) + amps(27)
  __shared__ float gbuf[512];
  __shared__ float prj[27];

  // ---- weights into registers (reused all 15 steps)
  float4 wih[9], whh[32];
  {
    const float4* wi = (const float4*)(W_ih + tid*36);
    #pragma unroll
    for (int k = 0; k < 9; ++k) wih[k] = wi[k];
    const float4* wh = (const float4*)(W_hh + tid*H);
    #pragma unroll
    for (int k = 0; k < 32; ++k) whh[k] = wh[k];
  }
  const float bias = b_ih[tid] + b_hh[tid];

  // ---- prj unit ownership: waves 1-7 only, u = (w-1) + 7i  (covers 0..26)
  float2 wpv[4]; float bpv[4];
  #pragma unroll
  for (int i = 0; i < 4; ++i) {
    int u = (w >= 1) ? (w - 1) + 7*i : 99;
    if (u < 27) { wpv[i] = *(const float2*)(Wp + u*H + 2*lane); bpv[i] = bp[u]; }
    else        { wpv[i] = make_float2(0.f, 0.f); bpv[i] = 0.f; }
  }

  // ---- c and h register-resident on EVERY wave (redundant copies, 2/lane)
  float cc0 = c0[b*H + 2*lane], cc1 = c0[b*H + 2*lane + 1];
  float h0v = h0[b*H + 2*lane], h1v = h0[b*H + 2*lane + 1];

  // ---- pristine psi0 in wave-0 registers: flat = j*64 + lane
  float pr0[8], pi0[8], norm0 = 0.f;
  if (w == 0) {
    #pragma unroll
    for (int j = 0; j < 8; ++j) {
      pr0[j] = rho[b*1024 + j*64 + lane];
      pi0[j] = rho[b*1024 + 512 + j*64 + lane];
    }
    float ls = 0.f;
    #pragma unroll
    for (int j = 0; j < 8; ++j) ls += pr0[j]*pr0[j] + pi0[j]*pi0[j];
    norm0 = wave_red_sum(ls);
  }

  // ---- init x in LDS; t=0 mats straight from global inputs
  if (tid < NQ)  xh[tid]      = snapshot[b*NQ + tid];
  if (tid < 27)  xh[NQ + tid] = bcv[b*27 + tid];
  if (tid < NQ) {
    float s  = snapshot[b*NQ + tid];
    float v0 = bcv[b*27 + tid*3];
    float v1 = bcv[b*27 + tid*3 + 1];
    float v2 = bcv[b*27 + tid*3 + 2];
    mats[(b*S + 0)*NQ + tid] = make_float4(
        0.5f*(1.f + 3.f*s*v2), 1.5f*s*v0, -1.5f*s*v1, 0.5f*(1.f - 3.f*s*v2));
  }
  __syncthreads();                                        // B0: xh ready

  // ---- pre-loop ghh from h0 registers (readlane broadcast, all waves)
  float ghh = ghh_rl4(whh, h0v, h1v, bias);

  for (int t = 1; t < S; ++t) {
    // ---- X: finish gates = ghh + W_ih * x   (9 LDS b128 reads)
    {
      const float4* x4 = (const float4*)xh;
      float g0 = ghh, g1 = 0.f, g2 = 0.f, g3 = 0.f;
      #pragma unroll
      for (int k = 0; k < 9; ++k) {
        float4 wv = wih[k], xv = x4[k];
        g0 += wv.x*xv.x; g1 += wv.y*xv.y; g2 += wv.z*xv.z; g3 += wv.w*xv.w;
      }
      gbuf[tid] = (g0 + g1) + (g2 + g3);
    }
    __syncthreads();                                      // B1: gbuf ready

    // ---- C: cell update, every wave redundantly (h in registers)
    {
      float2 gI = *(const float2*)(gbuf + 2*lane);
      float2 gF = *(const float2*)(gbuf + 128 + 2*lane);
      float2 gG = *(const float2*)(gbuf + 256 + 2*lane);
      float2 gO = *(const float2*)(gbuf + 384 + 2*lane);
      cc0 = sigf(gF.x)*cc0 + sigf(gI.x)*tanhfast(gG.x);
      cc1 = sigf(gF.y)*cc1 + sigf(gI.y)*tanhfast(gG.y);
      h0v = sigf(gO.x)*tanhfast(cc0);
      h1v = sigf(gO.y)*tanhfast(cc1);
    }
    // ---- waves 1-7: projection logits (DPP wave reduction, reg h);
    //      wave 0: its own next-step ghh, hidden under their prj.
    if (w > 0) {
      #pragma unroll
      for (int i = 0; i < 4; ++i) {
        float p = wave_red_sum(wpv[i].x*h0v + wpv[i].y*h1v);
        int u = (w - 1) + 7*i;
        if (u < 27 && lane == 0) prj[u] = p + bpv[i];
      }
    } else if (t < S - 1) {
      ghh = ghh_rl4(whh, h0v, h1v, bias);
    }
    __syncthreads();                                      // B2: prj ready

    // ---- wave 0: softmax -> amps; deferred-norm collapse; emit
    //      (waves 1-7 skip straight to their ghh below -> overlap)
    if (w == 0) {
      float a1 = 0.f, a2 = 0.f, a3 = 0.f;
      float k0v = 0.f, k1rv = 0.f, k1iv = 0.f;
      if (lane < NQ) {
        float l0 = prj[lane*3], l1 = prj[lane*3+1], l2 = prj[lane*3+2];
        float mx = fmaxf(l0, fmaxf(l1, l2));
        float e0 = __expf(l0 - mx), e1 = __expf(l1 - mx), e2 = __expf(l2 - mx);
        float inv = RCP(e0 + e1 + e2);
        a1 = sqrtf(e0*inv); a2 = sqrtf(e1*inv); a3 = sqrtf(e2*inv);
        float an = sqrtf(a1*a1 + a2*a2 + a3*a3);
        float t3 = a3 + an;
        float n1 = RSQ(2.f*an*t3);
        k0v = n1*t3; k1rv = n1*a1; k1iv = -n1*a2;  // conj(p+) coefficients
      }
      float part[9];

      // q0: register bit 2 (no cross-lane)
      float r4[4], i4[4];
      {
        const float K0 = RL(k0v,0), K1r = RL(k1rv,0), K1i = RL(k1iv,0);
        float lp = 0.f;
        #pragma unroll
        for (int j = 0; j < 4; ++j) {
          r4[j] = K0*pr0[j] + K1r*pr0[j+4] - K1i*pi0[j+4];
          i4[j] = K0*pi0[j] + K1r*pi0[j+4] + K1i*pr0[j+4];
          lp += r4[j]*r4[j] + i4[j]*i4[j];
        }
        part[0] = lp;
      }
      // q1: register bit 1
      float r2[2], i2[2];
      {
        const float K0 = RL(k0v,1), K1r = RL(k1rv,1), K1i = RL(k1iv,1);
        float lp = 0.f;
        #pragma unroll
        for (int j = 0; j < 2; ++j) {
          r2[j] = K0*r4[j] + K1r*r4[j+2] - K1i*i4[j+2];
          i2[j] = K0*i4[j] + K1r*i4[j+2] + K1i*r4[j+2];
          lp += r2[j]*r2[j] + i2[j]*i2[j];
        }
        part[1] = lp;
      }
      // q2: register bit 0
      float wr, wi_;
      {
        const float K0 = RL(k0v,2), K1r = RL(k1rv,2), K1i = RL(k1iv,2);
        wr  = K0*r2[0] + K1r*r2[1] - K1i*i2[1];
        wi_ = K0*i2[0] + K1r*i2[1] + K1i*r2[1];
        part[2] = wr*wr + wi_*wi_;
      }
      // q3, q4: partner lane+half via bpermute (half = 32, 16)
      #pragma unroll
      for (int q = 3; q < 5; ++q) {
        const int half = 32 >> (q - 3);
        const float K0 = RL(k0v,q), K1r = RL(k1rv,q), K1i = RL(k1iv,q);
        float pr = __shfl(wr,  lane + half, 64);
        float pi = __shfl(wi_, lane + half, 64);
        float nr = K0*wr  + K1r*pr - K1i*pi;
        float ni = K0*wi_ + K1r*pi + K1i*pr;
        wr = nr; wi_ = ni;
        part[q] = (lane < half) ? (nr*nr + ni*ni) : 0.f;
      }
      // q5..q8: partner lane+half via row_ror:(16-half)  [source = i+half]
      #pragma unroll
      for (int q = 5; q < NQ; ++q) {
        const int half = 32 >> (q - 3);
        const float K0 = RL(k0v,q), K1r = RL(k1rv,q), K1i = RL(k1iv,q);
        float pr, pi;
        if      (q == 5) { pr = DPP_ROR(wr, 8);  pi = DPP_ROR(wi_, 8);  }
        else if (q == 6) { pr = DPP_ROR(wr, 12); pi = DPP_ROR(wi_, 12); }
        else if (q == 7) { pr = DPP_ROR(wr, 14); pi = DPP_ROR(wi_, 14); }
        else             { pr = DPP_ROR(wr, 15); pi = DPP_ROR(wi_, 15); }
        float nr = K0*wr  + K1r*pr - K1i*pi;
        float ni = K0*wi_ + K1r*pi + K1i*pr;
        wr = nr; wi_ = ni;
        part[q] = (lane < half) ? (nr*nr + ni*ni) : 0.f;
      }
      // batched norm reductions (independent DPP chains)
      float L[9];
      #pragma unroll
      for (int q = 0; q < NQ; ++q) L[q] = wave_red_sum(part[q]);
      // s values: independent rcp per qubit (parallel, not a divide chain)
      float sv = 2.f*L[0] - norm0;
      #pragma unroll
      for (int q = 1; q < NQ; ++q) {
        float r = 2.f*L[q]*RCP(L[q-1]) - 1.f;
        sv = (lane == q) ? r : sv;
      }
      // emit: new x = [snap, amps] and mats row for this t
      if (lane < NQ) {
        xh[lane] = sv;
        xh[9 + lane*3]     = a1;
        xh[9 + lane*3 + 1] = a2;
        xh[9 + lane*3 + 2] = a3;
        mats[(b*S + t)*NQ + lane] = make_float4(
            0.5f*(1.f + 3.f*sv*a3), 1.5f*sv*a1,
            -1.5f*sv*a2,            0.5f*(1.f - 3.f*sv*a3));
      }
    } else if (t < S - 1) {
      // ---- waves 1-7: next-step ghh from register h (runs during
      //      wave 0's collapse; wave 0's own ghh already done pre-B2)
      ghh = ghh_rl4(whh, h0v, h1v, bias);
    }
    __syncthreads();                                      // B3: xh ready
  }

  if (tid < 27) last_bv[b*27 + tid] = xh[9 + tid];
}

// ---------------------------------------------------------------------------
// Kernel 2: out[b] = (1/S) sum_t Top(q0..3,16x16) (x) Bot(q4..8,32x32).
// v5: 2 rT x 4 rB rows per block, grid (64,16) = 1024 blocks.
// Staging writes are ENTRY-STRIDED (thread e writes entries e+512i) so
// consecutive lanes hit consecutive float2 -> 2-way bank aliasing (free).
// b128 bot reads (8 distinct addrs/wave = broadcast), nontemporal stores.
// ---------------------------------------------------------------------------
__device__ __forceinline__ void herm_entry(float4 m, int rb, int cb, float& er, float& ei) {
  if (rb == 0) { if (cb == 0) { er = m.x; ei = 0.f; } else { er = m.y; ei = m.z; } }
  else         { if (cb == 0) { er = m.y; ei = -m.z; } else { er = m.w; ei = 0.f; } }
}

__device__ __forceinline__ void nt_store4(float* p, float x, float y, float z, float w) {
  vfloat4 v; v.x = x; v.y = y; v.z = z; v.w = w;
  __builtin_nontemporal_store(v, (vfloat4*)p);
}

__global__ __launch_bounds__(512, 2)
void kron_kernel(const float4* __restrict__ mats_g, float* __restrict__ out)
{
  const int b   = blockIdx.y;
  const int bm  = blockIdx.x;          // rTp = bm>>3 (rT pair), rg = bm&7 (rB grp)
  const int tid = threadIdx.x;
  const int rTp = bm >> 3;
  const int rg  = bm & 7;

  __shared__ float4 matsh[S*NQ];                  // 2.3 KB
  __shared__ float2 top[S][2][16];                // 4 KB  [t][rTi][cT]
  __shared__ __align__(16) float2 bot[4][S][32];  // 16 KB [r][t][cB]

  if (tid < S*NQ) matsh[tid] = mats_g[b*S*NQ + tid];
  __syncthreads();

  {                                    // top: 512 entries, one per thread
    int t = tid >> 5, rTi = (tid >> 4) & 1, cT = tid & 15;
    int rT = rTp*2 + rTi;
    float re = 1.f, im = 0.f;
    #pragma unroll
    for (int q = 0; q < 4; ++q) {
      int rb = (rT >> (3 - q)) & 1, cb = (cT >> (3 - q)) & 1;
      float er, ei; herm_entry(matsh[t*NQ + q], rb, cb, er, ei);
      float nr = re*er - im*ei; im = re*ei + im*er; re = nr;
    }
    top[t][rTi][cT] = make_float2(re, im);
  }
  // bot: 2048 entries, entry-strided (conflict-free writes)
  #pragma unroll
  for (int i = 0; i < 4; ++i) {
    int n  = tid + 512*i;
    int r_ = n >> 9, t_ = (n >> 5) & 15, cB = n & 31;
    int rB = rg*4 + r_;
    float re = 1.f, im = 0.f;
    #pragma unroll
    for (int q = 0; q < 5; ++q) {
      int rb = (rB >> (4 - q)) & 1, cb = (cB >> (4 - q)) & 1;
      float er, ei; herm_entry(matsh[t_*NQ + 4 + q], rb, cb, er, ei);
      float nr = re*er - im*ei; im = re*ei + im*er; re = nr;
    }
    bot[r_][t_][cB] = make_float2(re, im);
  }
  __syncthreads();

  const int rb = tid >> 7;             // rB index within block (0..3)
  const int c0 = (tid & 127) << 2;     // 4 consecutive cols
  const int cT = c0 >> 5, cB = c0 & 31;
  float4 a0r = make_float4(0,0,0,0), a0i = make_float4(0,0,0,0);
  float4 a1r = make_float4(0,0,0,0), a1i = make_float4(0,0,0,0);
  #pragma unroll
  for (int t = 0; t < S; ++t) {
    float4 b01 = *(const float4*)&bot[rb][t][cB];      // cols cB, cB+1
    float4 b23 = *(const float4*)&bot[rb][t][cB + 2];  // cols cB+2, cB+3
    float2 tA = top[t][0][cT];
    float2 tB = top[t][1][cT];
    a0r.x += tA.x*b01.x - tA.y*b01.y;  a0i.x += tA.x*b01.y + tA.y*b01.x;
    a0r.y += tA.x*b01.z - tA.y*b01.w;  a0i.y += tA.x*b01.w + tA.y*b01.z;
    a0r.z += tA.x*b23.x - tA.y*b23.y;  a0i.z += tA.x*b23.y + tA.y*b23.x;
    a0r.w += tA.x*b23.z - tA.y*b23.w;  a0i.w += tA.x*b23.w + tA.y*b23.z;
    a1r.x += tB.x*b01.x - tB.y*b01.y;  a1i.x += tB.x*b01.y + tB.y*b01.x;
    a1r.y += tB.x*b01.z - tB.y*b01.w;  a1i.y += tB.x*b01.w + tB.y*b01.z;
    a1r.z += tB.x*b23.x - tB.y*b23.y;  a1i.z += tB.x*b23.y + tB.y*b23.x;
    a1r.w += tB.x*b23.z - tB.y*b23.w;  a1i.w += tB.x*b23.w + tB.y*b23.z;
  }
  const float invS = 1.f/16.f;
  const int rowA = (rTp*2)*32 + rg*4 + rb;   // rT = 2*rTp
  const int rowB = rowA + 32;                // rT = 2*rTp + 1
  size_t baseA = ((size_t)b*2)*DD + (size_t)rowA*D + c0;
  size_t baseB = ((size_t)b*2)*DD + (size_t)rowB*D + c0;
  nt_store4(out + baseA,      a0r.x*invS, a0r.y*invS, a0r.z*invS, a0r.w*invS);
  nt_store4(out + baseA + DD, a0i.x*invS, a0i.y*invS, a0i.z*invS, a0i.w*invS);
  nt_store4(out + baseB,      a1r.x*invS, a1r.y*invS, a1r.z*invS, a1r.w*invS);
  nt_store4(out + baseB + DD, a1i.x*invS, a1i.y*invS, a1i.z*invS, a1i.w*invS);
}

extern "C" void kernel_launch(void* const* d_in, const int* in_sizes, int n_in,
                              void* d_out, int out_size, void* d_ws, size_t ws_size,
                              hipStream_t stream) {
  const float* snapshot = (const float*)d_in[0];
  const float* bcv      = (const float*)d_in[1];
  const float* rho      = (const float*)d_in[2];
  const float* h0       = (const float*)d_in[3];
  const float* c0       = (const float*)d_in[4];
  const float* W_ih     = (const float*)d_in[5];
  const float* W_hh     = (const float*)d_in[6];
  const float* b_ih     = (const float*)d_in[7];
  const float* b_hh     = (const float*)d_in[8];
  const float* Wp       = (const float*)d_in[9];
  const float* bp       = (const float*)d_in[10];

  float*  out     = (float*)d_out;
  float4* mats    = (float4*)d_ws;                 // 16*16*9 float4 = 36 KB
  float*  last_bv = out + (size_t)BB*2*DD;         // output chunk 1

  seq_kernel<<<BB, 512, 0, stream>>>(snapshot, bcv, rho, h0, c0,
                                     W_ih, W_hh, b_ih, b_hh, Wp, bp,
                                     mats, last_bv);

  dim3 grid(64, BB);
  kron_kernel<<<grid, 512, 0, stream>>>(mats, out);
}